// Round 6
// baseline (697.217 us; speedup 1.0000x reference)
//
#include <hip/hip_runtime.h>
#include <hip/hip_bf16.h>

typedef __bf16 bf16t;
typedef bf16t bf16x4 __attribute__((ext_vector_type(4)));
typedef bf16t bf16x8 __attribute__((ext_vector_type(8)));
typedef float f32x4 __attribute__((ext_vector_type(4)));

#define BT 8192      // B*T rows
#define TT 1024      // T
#define DM 1024      // d_model
#define DFF 4096

static __device__ __forceinline__ f32x4 mfma16(bf16x8 a, bf16x8 b, f32x4 c) {
  return __builtin_amdgcn_mfma_f32_16x16x32_bf16(a, b, c, 0, 0, 0);
}
static __device__ __forceinline__ bf16x8 ld8(const bf16t* p0, const bf16t* p1) {
  bf16x4 lo = *(const bf16x4*)p0;
  bf16x4 hi = *(const bf16x4*)p1;
  return __builtin_shufflevector(lo, hi, 0, 1, 2, 3, 4, 5, 6, 7);
}
static __device__ __forceinline__ f32x4 f4zero() {
  f32x4 z = {0.f, 0.f, 0.f, 0.f};
  return z;
}
static __device__ __forceinline__ f32x4 vmax4(f32x4 a, f32x4 b) {
  f32x4 r;
#pragma unroll
  for (int i = 0; i < 4; i++) r[i] = fmaxf(a[i], b[i]);
  return r;
}
// async global->LDS, 16 bytes per lane; lds dest = wave-uniform base + lane*16
static __device__ __forceinline__ void gld16(const bf16t* g, bf16t* l) {
  __builtin_amdgcn_global_load_lds((const __attribute__((address_space(1))) void*)g,
                                   (__attribute__((address_space(3))) void*)l, 16, 0, 0);
}

// ---------------- f32 -> bf16 convert (no transpose) ----------------
__global__ __launch_bounds__(256) void cvt_kernel(const float* __restrict__ in,
                                                  bf16t* __restrict__ out, long n) {
  long i = ((long)blockIdx.x * 256 + threadIdx.x) * 4;
  if (i >= n) return;
  f32x4 v = *(const f32x4*)&in[i];
  bf16x4 o = {(bf16t)v[0], (bf16t)v[1], (bf16t)v[2], (bf16t)v[3]};
  *(bf16x4*)&out[i] = o;
}

// ---------------- transpose-convert: out[N][M] = (bf16) in[M][N], 64x64 LDS tiles ----------------
__global__ __launch_bounds__(256) void tcvt_kernel(const float* __restrict__ in,
                                                   bf16t* __restrict__ out, int M, int N) {
  __shared__ float T[64][65];
  const int t = threadIdx.x;
  const int ty = t >> 6, tx = t & 63;
  const long n0 = (long)blockIdx.x * 64, m0 = (long)blockIdx.y * 64;
#pragma unroll
  for (int p = 0; p < 16; ++p) {
    int a = ty * 16 + p;
    T[a][tx] = in[(m0 + a) * N + n0 + tx];
  }
  __syncthreads();
#pragma unroll
  for (int p = 0; p < 16; ++p) {
    int r = ty * 16 + p;
    out[(n0 + r) * M + m0 + tx] = (bf16t)T[tx][r];
  }
}

// ---------------- V-transpose: qkv[M][3072] cols 2048.. -> vT[bh][64 d][1024 t] ----------------
__global__ __launch_bounds__(256) void vtrans_kernel(const bf16t* __restrict__ qkv,
                                                     bf16t* __restrict__ vT) {
  __shared__ bf16t T[64][72];
  const int bh = blockIdx.x;  // 0..127
  const int b = bh >> 4, h = bh & 15;
  const int tt = blockIdx.y;  // 0..15
  const int t = threadIdx.x;
  const int ty = t >> 6, tx = t & 63;
  const long srcbase = ((long)b * TT + tt * 64) * 3072 + 2048 + h * 64;
#pragma unroll
  for (int p = 0; p < 16; ++p) {
    int a = ty * 16 + p;
    T[a][tx] = qkv[srcbase + (long)a * 3072 + tx];
  }
  __syncthreads();
  const long dstbase = ((long)bh * 64) * 1024 + tt * 64;
#pragma unroll
  for (int p = 0; p < 16; ++p) {
    int d = ty * 16 + p;
    vT[dstbase + (long)d * 1024 + tx] = T[tx][d];
  }
}

// ---------------- pack Wq/Wk/Wv [H][D][Dh] -> transposed [3072][1024] bf16 ----------------
__global__ __launch_bounds__(256) void pack_qkv_t_kernel(const float* __restrict__ Wq,
                                                         const float* __restrict__ Wk,
                                                         const float* __restrict__ Wv,
                                                         bf16t* __restrict__ WT) {
  __shared__ float T[64][65];
  const int bx = blockIdx.x;  // 0..47 : sel*16 + h
  const int sel = bx >> 4, h = bx & 15;
  const float* src = ((sel == 0) ? Wq : (sel == 1) ? Wk : Wv) + (long)h * 65536;  // [1024][64]
  const long nbase = (long)sel * 1024 + h * 64;
  const long m0 = (long)blockIdx.y * 64;  // d tile
  const int t = threadIdx.x;
  const int ty = t >> 6, tx = t & 63;
#pragma unroll
  for (int p = 0; p < 16; ++p) {
    int a = ty * 16 + p;
    T[a][tx] = src[(m0 + a) * 64 + tx];  // [d_local][kk]
  }
  __syncthreads();
#pragma unroll
  for (int p = 0; p < 16; ++p) {
    int r = ty * 16 + p;  // kk
    WT[(nbase + r) * 1024 + m0 + tx] = (bf16t)T[tx][r];
  }
}

__global__ __launch_bounds__(256) void pack_bias_kernel(const float* __restrict__ bq,
                                                        const float* __restrict__ bk,
                                                        const float* __restrict__ bv,
                                                        float* __restrict__ bqkv) {
  int i = blockIdx.x * 256 + threadIdx.x;
  if (i >= 3072) return;
  int sel = i >> 10, c = i & 1023;
  bqkv[i] = ((sel == 0) ? bq : (sel == 1) ? bk : bv)[c];
}

// ---------------- GEMM: C[M,N] = A[M,K](bf16) * B^T  where Bt is [N][K](bf16) ----------------
// 128x128 tile, BK=32, global_load_lds staging, XOR-swizzled LDS (T2, both-sides),
// TRIPLE-buffered with counted vmcnt (T4): stage tile t+2 during compute of tile t;
// end-of-step waits vmcnt(4) (next tile's 4 loads are the oldest of 8 in flight) —
// loads are never drained to 0 in the main loop. Raw s_barrier + sched_barrier(0)
// (rule #18) replace __syncthreads' vmcnt(0) drain.
// 1-D grid with XCD-chunked swizzle (T1) + column-group-of-8 super-tile order for L2.
template <int EPI>
__global__ __launch_bounds__(256) void gemm_kernel(
    const bf16t* __restrict__ A, const bf16t* __restrict__ Bt,
    const float* __restrict__ bias, const float* __restrict__ resid,
    void* __restrict__ Cout, int M, int N, int K) {
  __shared__ bf16t As[3 * 128 * 32];
  __shared__ bf16t Bs[3 * 128 * 32];
  const int tid = threadIdx.x;
  const int lane = tid & 63;
  const int wid = tid >> 6;
  const int wr = wid >> 1, wc = wid & 1;
  const int g = lane >> 4, lr = lane & 15;

  const int gy = M >> 7;
  const int nwg = gridDim.x;
  const int chunk = nwg >> 3;
  const int wg = blockIdx.x;
  const int lid = (wg & 7) * chunk + (wg >> 3);
  const int gsz = gy << 3;  // 8 * gy
  const int group = lid / gsz;
  const int rem = lid - group * gsz;
  const int rr = rem >> 3;
  const int cc = (group << 3) + (rem & 7);
  const long brow = (long)rr * 128;
  const long bcol = (long)cc * 128;

  f32x4 acc[4][4];
#pragma unroll
  for (int i = 0; i < 4; i++)
#pragma unroll
    for (int j = 0; j < 4; j++) acc[i][j] = f4zero();

  const int srow = tid >> 2;                       // 0..63 row within round
  const int csrc = (tid & 3) ^ ((tid >> 3) & 3);   // pre-swizzled global 16B-chunk
  const bf16t* gA = &A[(brow + srow) * (long)K + 8 * csrc];
  const bf16t* gB = &Bt[(bcol + srow) * (long)K + 8 * csrc];
  bf16t* lA = As + wid * 512;  // wave-uniform base
  bf16t* lB = Bs + wid * 512;

  const int xsw = ((lr >> 1) & 3) << 3;
  const int ra0 = (4 * g) ^ xsw;
  const int ra1 = (16 + 4 * g) ^ xsw;

  auto stage = [&](int buf, int k0) {
    gld16(gA + k0, lA + buf * 4096);
    gld16(gA + k0 + (long)64 * K, lA + buf * 4096 + 2048);
    gld16(gB + k0, lB + buf * 4096);
    gld16(gB + k0 + (long)64 * K, lB + buf * 4096 + 2048);
  };

  const int nt = K >> 5;
  // prologue: stage tiles 0 and 1; wait for tile 0 (leave tile 1 in flight)
  stage(0, 0);
  stage(1, 32);
  asm volatile("s_waitcnt vmcnt(4)" ::: "memory");
  __builtin_amdgcn_s_barrier();
  __builtin_amdgcn_sched_barrier(0);

  for (int t = 0; t < nt; ++t) {
    const int k2 = (t + 2) << 5;
    const bool pf = (k2 < K);
    if (pf) stage((t + 2) % 3, k2);

    const bf16t* bufA = As + (t % 3) * 4096;
    const bf16t* bufB = Bs + (t % 3) * 4096;
    bf16x8 af[4], bfv[4];
#pragma unroll
    for (int i = 0; i < 4; i++) {
      const bf16t* r = bufA + (wr * 64 + i * 16 + lr) * 32;
      af[i] = ld8(r + ra0, r + ra1);
    }
#pragma unroll
    for (int j = 0; j < 4; j++) {
      const bf16t* c = bufB + (wc * 64 + j * 16 + lr) * 32;
      bfv[j] = ld8(c + ra0, c + ra1);
    }
#pragma unroll
    for (int i = 0; i < 4; i++)
#pragma unroll
      for (int j = 0; j < 4; j++) acc[i][j] = mfma16(af[i], bfv[j], acc[i][j]);

    if (t + 1 < nt) {
      if (pf)
        asm volatile("s_waitcnt vmcnt(4)" ::: "memory");  // tile t+1 ready, t+2 in flight
      else
        asm volatile("s_waitcnt vmcnt(0)" ::: "memory");  // tail drain
      __builtin_amdgcn_s_barrier();
      __builtin_amdgcn_sched_barrier(0);
    }
  }

#pragma unroll
  for (int j = 0; j < 4; j++) {
    int col = (int)bcol + wc * 64 + j * 16 + lr;
    float bval = bias ? bias[col] : 0.f;
#pragma unroll
    for (int i = 0; i < 4; i++) {
      long row0 = brow + wr * 64 + i * 16 + 4 * g;
#pragma unroll
      for (int r2 = 0; r2 < 4; r2++) {
        long row = row0 + r2;
        float v = acc[i][j][r2] + bval;
        if (EPI == 0) {
          ((bf16t*)Cout)[row * N + col] = (bf16t)v;
        } else if (EPI == 1) {
          ((bf16t*)Cout)[row * N + col] = (bf16t)fmaxf(v, 0.f);
        } else {
          ((float*)Cout)[row * N + col] = v + resid[row * N + col];
        }
      }
    }
  }
}

// ---------------- flash attention, swapped-QK^T in-register softmax ----------------
__global__ __launch_bounds__(256) void attn_kernel(const bf16t* __restrict__ qkv,
                                                   const bf16t* __restrict__ vT,
                                                   bf16t* __restrict__ o) {
  const int bh = blockIdx.x;  // 0..127
  const int b = bh >> 4, h = bh & 15;
  const int qt = blockIdx.y;  // 0..15
  const int tid = threadIdx.x;
  const int lane = tid & 63;
  const int w = tid >> 6;
  const int g = lane >> 4, lr = lane & 15;

  __shared__ bf16t Qs[64 * 64];
  __shared__ bf16t Ks[2][64 * 64];
  __shared__ bf16t Vs[2][64 * 64];

  const long rowbase = (long)b * TT;
  const long qrow0 = rowbase + (long)qt * 64;

  const int srow_in_call = w * 8 + (lane >> 3);          // 0..31
  const int schunk = (lane & 7) ^ ((lane >> 3) & 7);     // swizzled source chunk
  const int soff = 8 * schunk;                           // elem offset in 64-elem row

  const bf16t* qsrc = &qkv[(qrow0 + srow_in_call) * 3072 + h * 64 + soff];
  const bf16t* ksrc = &qkv[(rowbase + srow_in_call) * 3072 + 1024 + h * 64 + soff];
  const bf16t* vsrc = &vT[((long)bh * 64 + srow_in_call) * 1024 + soff];
  bf16t* ldst = (bf16t*)((w * 8) * 64);  // numeric wave base offset (elems)

  auto stageQ = [&]() {
    gld16(qsrc, Qs + (size_t)ldst);
    gld16(qsrc + (long)32 * 3072, Qs + (size_t)ldst + 32 * 64);
  };
  auto stageK = [&](int buf, int kt) {
    const bf16t* s = ksrc + (long)kt * 64 * 3072;
    gld16(s, Ks[buf] + (size_t)ldst);
    gld16(s + (long)32 * 3072, Ks[buf] + (size_t)ldst + 32 * 64);
  };
  auto stageV = [&](int buf, int kt) {
    const bf16t* s = vsrc + kt * 64;
    gld16(s, Vs[buf] + (size_t)ldst);
    gld16(s + (long)32 * 1024, Vs[buf] + (size_t)ldst + 32 * 64);
  };

  stageQ();
  stageK(0, 0);
  stageV(0, 0);
  __syncthreads();  // vmcnt(0) drained: tile 0 + Q ready

  const int swk = (lr & 7) << 3;
  const int o0 = (4 * g) ^ swk, o1 = (16 + 4 * g) ^ swk;
  const int o2 = (32 + 4 * g) ^ swk, o3 = (48 + 4 * g) ^ swk;

  const bf16t* qrow = Qs + (w * 16 + lr) * 64;
  const bf16x8 qb_lo = ld8(qrow + o0, qrow + o1);  // d 0..31
  const bf16x8 qb_hi = ld8(qrow + o2, qrow + o3);  // d 32..63

  f32x4 acc_o[4];
#pragma unroll
  for (int j = 0; j < 4; j++) acc_o[j] = f4zero();
  float mrun = -1e30f, lrun = 0.f;  // stats for q = w*16 + lr (lr-domain)

  int cur = 0;
  for (int kt = 0; kt < 16; ++kt) {
    if (kt < 15) {
      stageK(cur ^ 1, kt + 1);
      stageV(cur ^ 1, kt + 1);
    }

    // S^T = K * Q^T : s[jt] holds S[k=jt*16+4g+r][q=lr]
    f32x4 s[4];
#pragma unroll
    for (int jt = 0; jt < 4; jt++) {
      const bf16t* krow = Ks[cur] + (jt * 16 + lr) * 64;
      bf16x8 ka_lo = ld8(krow + o0, krow + o1);
      bf16x8 ka_hi = ld8(krow + o2, krow + o3);
      f32x4 t = f4zero();
      t = mfma16(ka_lo, qb_lo, t);
      t = mfma16(ka_hi, qb_hi, t);
      s[jt] = t;
    }

#pragma unroll
    for (int jt = 0; jt < 4; jt++)
#pragma unroll
      for (int r = 0; r < 4; r++) s[jt][r] *= 0.125f;

    f32x4 mv = vmax4(vmax4(s[0], s[1]), vmax4(s[2], s[3]));
    float tm = fmaxf(fmaxf(mv[0], mv[1]), fmaxf(mv[2], mv[3]));
    tm = fmaxf(tm, __shfl_xor(tm, 16, 64));
    tm = fmaxf(tm, __shfl_xor(tm, 32, 64));

    float mnew = fmaxf(mrun, tm);
    float corr = __expf(mrun - mnew);
    mrun = mnew;

    f32x4 sv = f4zero();
#pragma unroll
    for (int jt = 0; jt < 4; jt++)
#pragma unroll
      for (int r = 0; r < 4; r++) {
        float pv = __expf(s[jt][r] - mnew);
        s[jt][r] = pv;
        sv[r] += pv;
      }
    float tsum = sv[0] + sv[1] + sv[2] + sv[3];
    tsum += __shfl_xor(tsum, 16, 64);
    tsum += __shfl_xor(tsum, 32, 64);
    lrun = lrun * corr + tsum;

#pragma unroll
    for (int r = 0; r < 4; r++) {
      float cq = __shfl(corr, 20 * g + r, 64);
#pragma unroll
      for (int dt = 0; dt < 4; dt++) acc_o[dt][r] *= cq;
    }

    bf16x8 pa0, pa1;
#pragma unroll
    for (int r = 0; r < 4; r++) {
      pa0[r] = (bf16t)s[0][r];
      pa0[r + 4] = (bf16t)s[1][r];
      pa1[r] = (bf16t)s[2][r];
      pa1[r + 4] = (bf16t)s[3][r];
    }

#pragma unroll
    for (int dt = 0; dt < 4; dt++) {
      const bf16t* vrow = Vs[cur] + (dt * 16 + lr) * 64;
      bf16x8 vb_lo = ld8(vrow + o0, vrow + o1);
      bf16x8 vb_hi = ld8(vrow + o2, vrow + o3);
      acc_o[dt] = mfma16(pa0, vb_lo, acc_o[dt]);
      acc_o[dt] = mfma16(pa1, vb_hi, acc_o[dt]);
    }

    __syncthreads();  // next tile staged + guards buffer reuse
    cur ^= 1;
  }

  float inv = 1.0f / lrun;
#pragma unroll
  for (int r = 0; r < 4; r++) {
    float iq = __shfl(inv, 20 * g + r, 64);
    long row = qrow0 + w * 16 + 4 * g + r;
#pragma unroll
    for (int dt = 0; dt < 4; dt++) {
      o[row * (long)DM + h * 64 + dt * 16 + lr] = (bf16t)(acc_o[dt][r] * iq);
    }
  }
}

// ---------------- LayerNorm: x[row][1024] f32 -> bf16 out and/or f32 out ----------------
__global__ __launch_bounds__(256) void ln_kernel(const float* __restrict__ x,
                                                 const float* __restrict__ gamma,
                                                 const float* __restrict__ beta,
                                                 bf16t* __restrict__ out_bf,
                                                 float* __restrict__ out_f32) {
  const long row = blockIdx.x;
  const int tid = threadIdx.x;
  const float* xr = x + row * DM;
  f32x4 v = *(const f32x4*)&xr[tid * 4];
  float s = v[0] + v[1] + v[2] + v[3];
  float ss = v[0] * v[0] + v[1] * v[1] + v[2] * v[2] + v[3] * v[3];
#pragma unroll
  for (int m = 1; m < 64; m <<= 1) {
    s += __shfl_xor(s, m, 64);
    ss += __shfl_xor(ss, m, 64);
  }
  __shared__ float red[8];
  const int w = tid >> 6, lane = tid & 63;
  if (lane == 0) {
    red[w] = s;
    red[4 + w] = ss;
  }
  __syncthreads();
  s = red[0] + red[1] + red[2] + red[3];
  ss = red[4] + red[5] + red[6] + red[7];
  float mean = s * (1.f / DM);
  float var = ss * (1.f / DM) - mean * mean;
  float inv = rsqrtf(var + 1e-5f);
  f32x4 ga = *(const f32x4*)&gamma[tid * 4];
  f32x4 be = *(const f32x4*)&beta[tid * 4];
  bf16x4 ob;
  f32x4 of;
#pragma unroll
  for (int c = 0; c < 4; c++) {
    float y = (v[c] - mean) * inv * ga[c] + be[c];
    ob[c] = (bf16t)y;
    of[c] = y;
  }
  long base = row * DM + tid * 4;
  if (out_bf) *(bf16x4*)&out_bf[base] = ob;
  if (out_f32) *(f32x4*)&out_f32[base] = of;
}

extern "C" void kernel_launch(void* const* d_in, const int* in_sizes, int n_in,
                              void* d_out, int out_size, void* d_ws, size_t ws_size,
                              hipStream_t stream) {
  const float* z = (const float*)d_in[0];
  const float* Wq = (const float*)d_in[1];
  const float* bq = (const float*)d_in[2];
  const float* Wk = (const float*)d_in[3];
  const float* bk = (const float*)d_in[4];
  const float* Wv = (const float*)d_in[5];
  const float* bv = (const float*)d_in[6];
  const float* Wo = (const float*)d_in[7];
  const float* bo = (const float*)d_in[8];
  const float* W1 = (const float*)d_in[9];
  const float* b1 = (const float*)d_in[10];
  const float* W2 = (const float*)d_in[11];
  const float* b2 = (const float*)d_in[12];
  const float* g1 = (const float*)d_in[13];
  const float* be1 = (const float*)d_in[14];
  const float* g2 = (const float*)d_in[15];
  const float* be2 = (const float*)d_in[16];

  char* p = (char*)d_ws;
  auto alloc = [&](size_t bytes) {
    char* r = p;
    p += (bytes + 255) & ~(size_t)255;
    return r;
  };
  bf16t* wqkvT = (bf16t*)alloc((size_t)3072 * 1024 * 2);  // [3072][1024]
  float* bqkv = (float*)alloc((size_t)3072 * 4);
  bf16t* woT = (bf16t*)alloc((size_t)1024 * 1024 * 2);    // [1024][1024]
  bf16t* w1T = (bf16t*)alloc((size_t)4096 * 1024 * 2);    // [4096][1024]
  bf16t* w2T = (bf16t*)alloc((size_t)1024 * 4096 * 2);    // [1024][4096]
  bf16t* act = (bf16t*)alloc((size_t)BT * 1024 * 2);
  bf16t* obuf = (bf16t*)alloc((size_t)BT * 1024 * 2);
  bf16t* big = (bf16t*)alloc((size_t)BT * 4096 * 2);  // qkv[M][3072] / ffn-h[M][4096]
  float* tbuf = (float*)alloc((size_t)BT * 1024 * 4);
  float* residf = (float*)alloc((size_t)BT * 1024 * 4);
  // vT aliases tbuf (disjoint lifetimes)
  bf16t* vT = (bf16t*)tbuf;  // [128][64][1024] = 16 MB

  pack_qkv_t_kernel<<<dim3(48, 16), dim3(256), 0, stream>>>(Wq, Wk, Wv, wqkvT);
  pack_bias_kernel<<<dim3(12), dim3(256), 0, stream>>>(bq, bk, bv, bqkv);
  tcvt_kernel<<<dim3(16, 16), dim3(256), 0, stream>>>(Wo, woT, 1024, 1024);
  tcvt_kernel<<<dim3(64, 16), dim3(256), 0, stream>>>(W1, w1T, 1024, 4096);
  tcvt_kernel<<<dim3(16, 64), dim3(256), 0, stream>>>(W2, w2T, 4096, 1024);
  cvt_kernel<<<dim3(8192), dim3(256), 0, stream>>>(z, act, (long)BT * 1024);

  for (int iter = 0; iter < 2; ++iter) {
    // QKV projection: grid = (3072/128)*(8192/128) = 24*64 = 1536
    gemm_kernel<0><<<dim3(1536), dim3(256), 0, stream>>>(
        act, wqkvT, bqkv, (const float*)nullptr, (void*)big, BT, 3072, 1024);
    // V transpose to [bh][d][t]
    vtrans_kernel<<<dim3(128, 16), dim3(256), 0, stream>>>(big, vT);
    // attention
    attn_kernel<<<dim3(128, 16), dim3(256), 0, stream>>>(big, vT, obuf);
    // O-projection + residual: grid = 8*64 = 512
    const float* rsrc = (iter == 0) ? z : residf;
    gemm_kernel<2><<<dim3(512), dim3(256), 0, stream>>>(
        obuf, woT, bo, rsrc, (void*)tbuf, BT, 1024, 1024);
    if (iter == 1) {
      ln_kernel<<<dim3(8192), dim3(256), 0, stream>>>(tbuf, g1, be1, (bf16t*)nullptr,
                                                      (float*)d_out);
      break;
    }
    ln_kernel<<<dim3(8192), dim3(256), 0, stream>>>(tbuf, g1, be1, act, residf);
    // FFN: grid = 32*64 = 2048 ; 8*64 = 512
    gemm_kernel<1><<<dim3(2048), dim3(256), 0, stream>>>(
        act, w1T, b1, (const float*)nullptr, (void*)big, BT, 4096, 1024);
    gemm_kernel<2><<<dim3(512), dim3(256), 0, stream>>>(
        big, w2T, b2, residf, (void*)tbuf, BT, 1024, 4096);
    ln_kernel<<<dim3(8192), dim3(256), 0, stream>>>(tbuf, g2, be2, act, residf);
  }
}